// Round 9
// baseline (137.161 us; speedup 1.0000x reference)
//
#include <hip/hip_runtime.h>

// ---------------------------------------------------------------------------
// memory_tree R9: all-register MLP, NO LDS weight staging.
// R8's 43us mlp was staging/phasing-bound: 8 waves/CU x 574KB weight stream
// through the LDS pipe (~15us floor) + 20 barrier phases. R9 reads ALL
// weights direct from L2 via L1: per-CU the 8 waves share the same stream,
// nt2 block (20KB) < L1 (32KB) => leader misses, followers hit; laggards
// self-synchronize on L1 hits. Zero barriers in the K-loop; LDS only for the
// final t1s transpose (6.7KB). W3 frags prefetched at nt2-top (latency under
// the 20-MFMA L2 chain).
// ---------------------------------------------------------------------------

typedef __bf16 bf16x8 __attribute__((ext_vector_type(8)));
typedef float f32x16 __attribute__((ext_vector_type(16)));

// ---- workspace layout (bytes) ---------------------------------------------
constexpr size_t OFF_W1B = 0;                    // [10 nt][64][8] bf16 = 10240
constexpr size_t OFF_W2B = 10240;                // [20 nt][20 ks][64][8] = 409600
constexpr size_t OFF_W3B = 419840;               // [4 nt][40 ks][64][8] = 163840
constexpr size_t OFF_W4B = 583680;               // [8 ks][64][8] = 8192
constexpr size_t OFF_T2N = 591872;               // [2048][16] bf16 = 65536
constexpr size_t OFF_T1N = 657408;               // [65536][16] bf16 = 2097152
constexpr size_t OFF_PART= 2754560;              // [64][2048] f32 = 524288
// total: 3278848 bytes (~3.3 MB)

__device__ __forceinline__ bf16x8 ld8(const __bf16* p) {
    return *reinterpret_cast<const bf16x8*>(p);
}
__device__ __forceinline__ f32x16 mfma32(bf16x8 a, bf16x8 b, f32x16 c) {
    return __builtin_amdgcn_mfma_f32_32x32x16_bf16(a, b, c, 0, 0, 0);
}

// Convert D-layout f32x16 (col=lane&31, row n=(reg&3)+8*(reg>>2)+4*hi) into
// two K=16 B-fragments (lane&31 = col, k = hi*8+e) covering n 0..15 / 16..31.
// f0 = [S02.r0, S13.r0, S02.r1, S13.r1], f1 = [S46.r0, S57.r0, S46.r1, S57.r1]
// where Sxy = permlane32_swap(Wx, Wy), Wj = cvt_pk(a[2j], a[2j+1]).
__device__ __forceinline__ void cvtswap(const f32x16& a, bf16x8& f0, bf16x8& f1) {
    unsigned w[8];
    #pragma unroll
    for (int j = 0; j < 8; j++)
        asm("v_cvt_pk_bf16_f32 %0, %1, %2" : "=v"(w[j]) : "v"(a[2*j]), "v"(a[2*j+1]));
    unsigned a0 = w[0], b0 = w[2]; asm("v_permlane32_swap_b32 %0, %1" : "+v"(a0), "+v"(b0));
    unsigned a1 = w[1], b1 = w[3]; asm("v_permlane32_swap_b32 %0, %1" : "+v"(a1), "+v"(b1));
    unsigned a2 = w[4], b2 = w[6]; asm("v_permlane32_swap_b32 %0, %1" : "+v"(a2), "+v"(b2));
    unsigned a3 = w[5], b3 = w[7]; asm("v_permlane32_swap_b32 %0, %1" : "+v"(a3), "+v"(b3));
    union { unsigned u[4]; bf16x8 v; } p, q;
    p.u[0] = a0; p.u[1] = a1; p.u[2] = b0; p.u[3] = b1; f0 = p.v;
    q.u[0] = a2; q.u[1] = a3; q.u[2] = b2; q.u[3] = b3; f1 = q.v;
}

// ---------------------------------------------------------------------------
// prep: weights -> bf16 frag-order with bias-as-k-channel; t2n normalize
// ---------------------------------------------------------------------------
__global__ void prep_kernel(const float* __restrict__ W1, const float* __restrict__ b1,
                            const float* __restrict__ W2, const float* __restrict__ b2,
                            const float* __restrict__ W3, const float* __restrict__ b3,
                            const float* __restrict__ W4, const float* __restrict__ b4,
                            const float* __restrict__ value, char* __restrict__ ws) {
    __bf16* W1B = (__bf16*)(ws + OFF_W1B);
    __bf16* W2B = (__bf16*)(ws + OFF_W2B);
    __bf16* W3B = (__bf16*)(ws + OFF_W3B);
    __bf16* W4B = (__bf16*)(ws + OFF_W4B);
    __bf16* T2N = (__bf16*)(ws + OFF_T2N);

    int idx = blockIdx.x * 256 + threadIdx.x;
    if (idx < 5120) {                        // W1B [nt<10][64][8]; k 16 (13 + bias@13)
        int e = idx & 7, lane = (idx >> 3) & 63, nt = idx >> 9;
        int n = nt*32 + (lane & 31);
        int k = (lane >> 5)*8 + e;
        float v = 0.0f;
        if (n < 300)       v = (k < 13) ? W1[n*13 + k] : (k == 13 ? b1[n] : 0.0f);
        else if (n == 300) v = (k == 13) ? 1.0f : 0.0f;    // h1 bias channel
        W1B[idx] = (__bf16)v;
        return;
    }
    idx -= 5120;
    if (idx < 204800) {                      // W2B [nt<20][ks<20][64][8]; k 320 (300+bias)
        int e = idx & 7, lane = (idx >> 3) & 63, r = idx >> 9;
        int ks = r % 20, nt = r / 20;
        int n = nt*32 + (lane & 31);
        int k = ks*16 + (lane >> 5)*8 + e;
        float v = 0.0f;
        if (n < 600)       v = (k < 300) ? W2[n*300 + k] : (k == 300 ? b2[n] : 0.0f);
        else if (n == 600) v = (k == 300) ? 1.0f : 0.0f;   // h2 bias channel
        W2B[idx] = (__bf16)v;
        return;
    }
    idx -= 204800;
    if (idx < 81920) {                       // W3B [nt<4][ks<40][64][8]; k 640 (600+bias)
        int e = idx & 7, lane = (idx >> 3) & 63, r = idx >> 9;
        int ks = r % 40, nt = r / 40;
        int n = nt*32 + (lane & 31);
        int k = ks*16 + (lane >> 5)*8 + e;
        float v = 0.0f;
        if (n < 100)       v = (k < 600) ? W3[n*600 + k] : (k == 600 ? b3[n] : 0.0f);
        else if (n == 100) v = (k == 600) ? 1.0f : 0.0f;   // h3 bias channel
        W3B[idx] = (__bf16)v;
        return;
    }
    idx -= 81920;
    if (idx < 4096) {                        // W4B [ks<8][64][8]; k 128 (100+bias@100)
        int e = idx & 7, lane = (idx >> 3) & 63, ks = idx >> 9;
        int n = lane & 31;
        int k = ks*16 + (lane >> 5)*8 + e;
        float v = 0.0f;
        if (n < 13) v = (k < 100) ? W4[n*100 + k] : (k == 100 ? b4[n] : 0.0f);
        W4B[idx] = (__bf16)v;                // rows 13..31 zero -> exact-0 pads
        return;
    }
    idx -= 4096;
    if (idx < 2048) {                        // t2n rows ([16], k>=13 zero)
        float v[13]; float s = 0.0f;
        #pragma unroll
        for (int k = 0; k < 13; k++) { v[k] = value[idx*13 + k]; s += v[k]*v[k]; }
        float inv = 1.0f / fmaxf(sqrtf(s), 1e-8f);
        #pragma unroll
        for (int k = 0; k < 13; k++) T2N[idx*16 + k] = (__bf16)(v[k] * inv);
        #pragma unroll
        for (int k = 13; k < 16; k++) T2N[idx*16 + k] = (__bf16)0.0f;
    }
}

// ---------------------------------------------------------------------------
// mlp: 128 rows/block, 4 waves (wave owns rows wave*32..+31, lane&31 = row).
// grid 512 => 8 waves/CU (cap: M/32 = 2048 waves). All weights direct from
// L2/L1; zero barriers in the K-loop; LDS = t1s transpose buffer only.
// ---------------------------------------------------------------------------
__global__ __launch_bounds__(256, 2) void mlp_kernel(const float* __restrict__ mem,
                                                     char* __restrict__ ws) {
    __shared__ float t1s[128*13];             // 6656 B

    const __bf16* W1B = (const __bf16*)(ws + OFF_W1B);
    const __bf16* W2B = (const __bf16*)(ws + OFF_W2B);
    const __bf16* W3B = (const __bf16*)(ws + OFF_W3B);
    const __bf16* W4B = (const __bf16*)(ws + OFF_W4B);
    __bf16* T1N = (__bf16*)(ws + OFF_T1N);

    const int tid = threadIdx.x;
    const int wave = tid >> 6, lane = tid & 63;
    const int l31 = lane & 31, hi = lane >> 5;
    const int bm0 = blockIdx.x * 128;
    const int m = bm0 + wave*32 + l31;        // this lane's memory row

    // ---- x B-fragment (k = hi*8+e; bias channel 1.0 at k=13) ----
    bf16x8 xf;
    {
        union { __bf16 h[8]; bf16x8 v; } u;
        const float* xr = mem + (size_t)m*13;
        if (hi == 0) {
            #pragma unroll
            for (int e = 0; e < 8; e++) u.h[e] = (__bf16)xr[e];
        } else {
            #pragma unroll
            for (int e = 0; e < 5; e++) u.h[e] = (__bf16)xr[8 + e];
            u.h[5] = (__bf16)1.0f;   // k=13 bias channel
            u.h[6] = (__bf16)0.0f;
            u.h[7] = (__bf16)0.0f;
        }
        xf = u.v;
    }

    // ---- L1: 10 n-tiles, one K=16 MFMA each -> afc[20] h1 B-fragments ----
    bf16x8 afc[20];
    #pragma unroll
    for (int nt = 0; nt < 10; nt++) {
        bf16x8 wf = ld8(W1B + (size_t)nt*512 + lane*8);
        f32x16 z = {};
        f32x16 a = mfma32(wf, xf, z);
        #pragma unroll
        for (int r = 0; r < 16; r++) a[r] = fmaxf(a[r], 0.0f);   // relu
        cvtswap(a, afc[2*nt], afc[2*nt + 1]);
    }

    // ---- fused L2+L3 over 20 n2-tiles; all weights direct from L2/L1 ----
    f32x16 acc3[4] = {};
    for (int nt2 = 0; nt2 < 20; nt2++) {
        // prefetch this step's W3 fragments (latency hides under L2 chain)
        bf16x8 wf3[8];
        #pragma unroll
        for (int n3 = 0; n3 < 4; n3++) {
            const __bf16* bp3 = W3B + ((size_t)(n3*40 + 2*nt2)*64 + lane)*8;
            wf3[2*n3]     = ld8(bp3);
            wf3[2*n3 + 1] = ld8(bp3 + 512);
        }
        // L2: acc2 = W2[nt2] x h1 (2-chain ILP, 20 direct loads + 20 MFMA)
        const __bf16* bp2 = W2B + (size_t)nt2*10240 + lane*8;
        f32x16 e0 = {}, e1 = {};
        #pragma unroll
        for (int ks = 0; ks < 20; ks += 2) {
            e0 = mfma32(ld8(bp2 + ks*512),       afc[ks],     e0);
            e1 = mfma32(ld8(bp2 + (ks + 1)*512), afc[ks + 1], e1);
        }
        // leaky + convert to h2 fragments
        #pragma unroll
        for (int r = 0; r < 16; r++) {
            float v = e0[r] + e1[r];
            e0[r] = fmaxf(v, 0.0f) + 0.01f*fminf(v, 0.0f);
        }
        bf16x8 h2f0, h2f1;
        cvtswap(e0, h2f0, h2f1);
        // L3: 8 MFMAs from prefetched frags
        #pragma unroll
        for (int n3 = 0; n3 < 4; n3++) {
            acc3[n3] = mfma32(wf3[2*n3],     h2f0, acc3[n3]);
            acc3[n3] = mfma32(wf3[2*n3 + 1], h2f1, acc3[n3]);
        }
    }

    // ---- L3 relu + convert -> L4 (W4 frags direct from global) ----
    f32x16 acc4 = {};
    #pragma unroll
    for (int n3 = 0; n3 < 4; n3++) {
        f32x16 h;
        #pragma unroll
        for (int r = 0; r < 16; r++) h[r] = fmaxf(acc3[n3][r], 0.0f);
        bf16x8 f0, f1;
        cvtswap(h, f0, f1);
        acc4 = mfma32(ld8(W4B + (size_t)(2*n3)*512 + lane*8),     f0, acc4);
        acc4 = mfma32(ld8(W4B + (size_t)(2*n3 + 1)*512 + lane*8), f1, acc4);
    }
    // leaky + scatter valid t1 values to LDS (pads are exact 0, skipped)
    const int mrow = wave*32 + l31;
    #pragma unroll
    for (int r = 0; r < 16; r++) {
        const int n4 = (r & 3) + 8*(r >> 2) + 4*hi;
        if (n4 < 13) {
            float v = acc4[r];
            t1s[mrow*13 + n4] = fmaxf(v, 0.0f) + 0.01f*fminf(v, 0.0f);
        }
    }
    __syncthreads();

    // ---- normalize rows -> T1N [16]-padded bf16 (32B/thread, coalesced) ----
    if (tid < 128) {
        float s = 0.0f, v[13];
        #pragma unroll
        for (int k = 0; k < 13; k++) { v[k] = t1s[tid*13 + k]; s += v[k]*v[k]; }
        const float inv = 1.0f / fmaxf(sqrtf(s), 1e-8f);
        union { __bf16 o[16]; bf16x8 f[2]; } u;
        #pragma unroll
        for (int k = 0; k < 13; k++) u.o[k] = (__bf16)(v[k] * inv);
        #pragma unroll
        for (int k = 13; k < 16; k++) u.o[k] = (__bf16)0.0f;
        bf16x8* dst = reinterpret_cast<bf16x8*>(T1N + (size_t)(bm0 + tid)*16);
        dst[0] = u.f[0];
        dst[1] = u.f[1];
    }
}

// ---------------------------------------------------------------------------
// sim: K=16 32x32 tiles. Wave owns one 32-b-row tile (af = 1 frag), streams
// 32 T1N m-tiles (64-way m-split, grid 1024), 2 tiles/step, max3 reduction.
// ---------------------------------------------------------------------------
__global__ __launch_bounds__(256) void sim_kernel(const char* __restrict__ ws_c,
                                                  float* __restrict__ part) {
    const char* ws = ws_c;
    const __bf16* T1N = (const __bf16*)(ws + OFF_T1N);
    const __bf16* T2N = (const __bf16*)(ws + OFF_T2N);
    const int wave = threadIdx.x >> 6, lane = threadIdx.x & 63;
    const int l31 = lane & 31, hi = lane >> 5;
    const int bgroup = blockIdx.x & 15, ms = blockIdx.x >> 4;   // 16 x 64 grid
    const int b0 = (bgroup*4 + wave) * 32;

    const bf16x8 af = ld8(T2N + (size_t)(b0 + l31)*16 + hi*8);
    const f32x16 zero = {};
    f32x16 mx;
    #pragma unroll
    for (int r = 0; r < 16; r++) mx[r] = -3.0e38f;

    #pragma unroll 4
    for (int mt = ms; mt < 2048; mt += 128) {
        bf16x8 bf0 = ld8(T1N + ((size_t)mt*32 + l31)*16 + hi*8);
        bf16x8 bf1 = ld8(T1N + ((size_t)(mt + 64)*32 + l31)*16 + hi*8);
        f32x16 d0 = mfma32(af, bf0, zero);
        f32x16 d1 = mfma32(af, bf1, zero);
        #pragma unroll
        for (int r = 0; r < 16; r++)
            mx[r] = fmaxf(mx[r], fmaxf(d0[r], d1[r]));   // -> v_max3_f32
    }
    #pragma unroll
    for (int off = 1; off <= 16; off <<= 1) {
        #pragma unroll
        for (int r = 0; r < 16; r++) mx[r] = fmaxf(mx[r], __shfl_xor(mx[r], off));
    }
    if (l31 == 0) {
        #pragma unroll
        for (int reg = 0; reg < 16; reg++)
            part[ms*2048 + b0 + (reg & 3) + 8*(reg >> 2) + 4*hi] = mx[reg];
    }
}

__global__ void reduce_kernel(const float* __restrict__ part, float* __restrict__ out) {
    int b = blockIdx.x*256 + threadIdx.x;
    if (b < 2048) {
        float m = part[b];
        #pragma unroll
        for (int ms = 1; ms < 64; ms++) m = fmaxf(m, part[ms*2048 + b]);
        out[b] = 23.0f * m;
    }
}

// ---------------------------------------------------------------------------
extern "C" void kernel_launch(void* const* d_in, const int* in_sizes, int n_in,
                              void* d_out, int out_size, void* d_ws, size_t ws_size,
                              hipStream_t stream) {
    const float* memory = (const float*)d_in[0];
    const float* value  = (const float*)d_in[1];
    const float* W1 = (const float*)d_in[2]; const float* b1 = (const float*)d_in[3];
    const float* W2 = (const float*)d_in[4]; const float* b2 = (const float*)d_in[5];
    const float* W3 = (const float*)d_in[6]; const float* b3 = (const float*)d_in[7];
    const float* W4 = (const float*)d_in[8]; const float* b4 = (const float*)d_in[9];
    char* ws = (char*)d_ws;
    float* part = (float*)(ws + OFF_PART);
    float* out = (float*)d_out;

    prep_kernel<<<1164, 256, 0, stream>>>(W1, b1, W2, b2, W3, b3, W4, b4, value, ws);
    mlp_kernel<<<512, 256, 0, stream>>>(memory, ws);
    sim_kernel<<<1024, 256, 0, stream>>>(ws, part);
    reduce_kernel<<<8, 256, 0, stream>>>(part, out);
}